// Round 8
// baseline (4968.784 us; speedup 1.0000x reference)
//
#include <hip/hip_runtime.h>
#include <cstdint>

// Problem constants
#define B_   64
#define Z_   512
#define U_   2048
#define T_   32
#define DIN_ 90
#define G4_  8192      // 4*U
#define STLD 12288     // st row stride (setup GEMM output: h at +l*4096, c at +l*4096+2048)

using bf16x8 = __attribute__((ext_vector_type(8))) short;   // 8 bf16 = 4 VGPRs
using f32x4  = __attribute__((ext_vector_type(4))) float;

#define MFMA(a, b, c) __builtin_amdgcn_mfma_f32_16x16x32_bf16((a), (b), (c), 0, 0, 0)

__device__ __forceinline__ unsigned short f2bf(float f) {
    unsigned int u = __float_as_uint(f);
    unsigned int r = (u + 0x7FFFu + ((u >> 16) & 1u)) >> 16;   // RNE
    return (unsigned short)r;
}
__device__ __forceinline__ float sigf(float x) { return 1.f / (1.f + expf(-x)); }

// ---------------- one-time weight prep ----------------

// Plain transpose: Wt[n*K + k] = bf16(W[(row_off+k)*N + n])
__global__ __launch_bounds__(256) void transpose_cvt(const float* __restrict__ W,
                                                     unsigned short* __restrict__ Wt,
                                                     int K, int N, int row_off)
{
    __shared__ float tile[32][33];
    const int nb = blockIdx.x * 32, kb = blockIdx.y * 32;
    const int tx = threadIdx.x & 31, ty = threadIdx.x >> 5;   // 32 x 8
    #pragma unroll
    for (int i = 0; i < 4; ++i)
        tile[ty + i * 8][tx] = W[(size_t)(row_off + kb + ty + i * 8) * N + nb + tx];
    __syncthreads();
    #pragma unroll
    for (int i = 0; i < 4; ++i)
        Wt[(size_t)(nb + ty + i * 8) * K + kb + tx] = f2bf(tile[tx][ty + i * 8]);
}

// Packed transpose for fused layer kernels: original col n = g*2048+u (g=n>>11)
// -> packed row (u>>3)*32 + g*8 + (u&7).  Block ut then owns packed rows
// [ut*32, ut*32+32) = units ut*8..ut*8+7 for all 4 gates, contiguously.
__global__ __launch_bounds__(256) void transpose_cvt_packed(const float* __restrict__ W,
                                                            unsigned short* __restrict__ Wt)
{
    __shared__ float tile[32][33];
    const int nb = blockIdx.x * 32, kb = blockIdx.y * 32;   // N=8192, K=2048
    const int tx = threadIdx.x & 31, ty = threadIdx.x >> 5;
    #pragma unroll
    for (int i = 0; i < 4; ++i)
        tile[ty + i * 8][tx] = W[(size_t)(kb + ty + i * 8) * G4_ + nb + tx];
    __syncthreads();
    #pragma unroll
    for (int i = 0; i < 4; ++i) {
        int n = nb + ty + i * 8;
        int g = n >> 11, u = n & 2047;
        int prow = ((u >> 3) << 5) + (g << 3) + (u & 7);
        Wt[(size_t)prow * U_ + kb + tx] = f2bf(tile[tx][ty + i * 8]);
    }
}

// w_outT[d][k] = bf16(w_out[k*90+d]) for d<90, else 0   (96 x 2048)
__global__ __launch_bounds__(256) void wout_cvt(const float* __restrict__ w_out,
                                                unsigned short* __restrict__ w_outT)
{
    int i = blockIdx.x * 256 + threadIdx.x;        // 96*2048
    int d = i >> 11, k = i & 2047;
    w_outT[i] = (d < DIN_) ? f2bf(w_out[(size_t)k * DIN_ + d]) : (unsigned short)0;
}

__global__ __launch_bounds__(256) void cvt_z(const float* __restrict__ z,
                                             unsigned short* __restrict__ zb)
{
    int i = blockIdx.x * 256 + threadIdx.x;        // 64*512
    zb[i] = f2bf(z[i]);
}

// initial h (bf16) and c (fp32) from the setup GEMM output st
__global__ __launch_bounds__(256) void hcinit(const float* __restrict__ st,
                                              unsigned short* __restrict__ h0,
                                              unsigned short* __restrict__ h1,
                                              unsigned short* __restrict__ h2s0,
                                              float* __restrict__ c0,
                                              float* __restrict__ c1,
                                              float* __restrict__ c2)
{
    int idx = blockIdx.x * 256 + threadIdx.x;      // 3*64*2048
    int u = idx & 2047, b = (idx >> 11) & 63, ly = idx >> 17;
    float hv = st[(size_t)b * STLD + ly * 4096 + u];
    float cv = st[(size_t)b * STLD + ly * 4096 + 2048 + u];
    unsigned short* h = (ly == 0) ? h0 : (ly == 1) ? h1 : h2s0;
    float* c = (ly == 0) ? c0 : (ly == 1) ? c1 : c2;
    h[(size_t)b * 2048 + u] = f2bf(hv);
    c[(size_t)b * 2048 + u] = cv;
}

// ---------------- setup GEMMs (K=512): out[64 x N] = A @ Wt^T + bias ----------------
__global__ __launch_bounds__(256) void gemm_plain(const unsigned short* __restrict__ A, int K,
                                                  const unsigned short* __restrict__ Wt,
                                                  const float* __restrict__ bias,
                                                  float* __restrict__ out, int ldo)
{
    const int t = threadIdx.x, wv = t >> 6, l = t & 63;
    const int wm = (wv >> 1) * 32, n0 = blockIdx.x * 64 + (wv & 1) * 32;
    const int lr = l & 15, lk = (l >> 4) * 8;
    f32x4 acc[2][2] = {};
    for (int kt = 0; kt < K; kt += 32) {
        bf16x8 a0 = *(const bf16x8*)(A + (size_t)(wm + lr) * K + kt + lk);
        bf16x8 a1 = *(const bf16x8*)(A + (size_t)(wm + 16 + lr) * K + kt + lk);
        bf16x8 w0 = *(const bf16x8*)(Wt + (size_t)(n0 + lr) * K + kt + lk);
        bf16x8 w1 = *(const bf16x8*)(Wt + (size_t)(n0 + 16 + lr) * K + kt + lk);
        acc[0][0] = MFMA(a0, w0, acc[0][0]);
        acc[0][1] = MFMA(a0, w1, acc[0][1]);
        acc[1][0] = MFMA(a1, w0, acc[1][0]);
        acc[1][1] = MFMA(a1, w1, acc[1][1]);
    }
    #pragma unroll
    for (int mi = 0; mi < 2; ++mi)
        #pragma unroll
        for (int ni = 0; ni < 2; ++ni)
            #pragma unroll
            for (int r = 0; r < 4; ++r) {
                int row = wm + mi * 16 + (l >> 4) * 4 + r;
                int col = n0 + ni * 16 + lr;
                out[(size_t)row * ldo + col] = acc[mi][ni][r] + bias[col];
            }
}

// ---------------- fused per-layer step kernel ----------------
// 4-stage register pipeline over K=2048; 8 loads (8 KB/wave) in flight.
// Prefetch overruns by <=256 B past the phase end (ws is padded / contiguous).
__device__ __forceinline__ void kphase2048(const unsigned short* __restrict__ ap,
                                           const unsigned short* __restrict__ wp,
                                           f32x4& acc0, f32x4& acc1)
{
    bf16x8 a0 = *(const bf16x8*)(ap + 0);
    bf16x8 w0 = *(const bf16x8*)(wp + 0);
    bf16x8 a1 = *(const bf16x8*)(ap + 32);
    bf16x8 w1 = *(const bf16x8*)(wp + 32);
    bf16x8 a2 = *(const bf16x8*)(ap + 64);
    bf16x8 w2 = *(const bf16x8*)(wp + 64);
    bf16x8 a3 = *(const bf16x8*)(ap + 96);
    bf16x8 w3 = *(const bf16x8*)(wp + 96);
    for (int kt = 0; kt < 2048; kt += 128) {
        acc0 = MFMA(a0, w0, acc0);
        a0 = *(const bf16x8*)(ap + kt + 128);
        w0 = *(const bf16x8*)(wp + kt + 128);
        acc1 = MFMA(a1, w1, acc1);
        a1 = *(const bf16x8*)(ap + kt + 160);
        w1 = *(const bf16x8*)(wp + kt + 160);
        acc0 = MFMA(a2, w2, acc0);
        a2 = *(const bf16x8*)(ap + kt + 192);
        w2 = *(const bf16x8*)(wp + kt + 192);
        acc1 = MFMA(a3, w3, acc1);
        a3 = *(const bf16x8*)(ap + kt + 224);
        w3 = *(const bf16x8*)(wp + kt + 224);
    }
}

// One launch = one LSTM layer step for ALL columns:
//   S = hOld @ rk  [+ xNew @ kW]  (+ base/bias at gate time) -> LSTM cell -> c, hNew
// grid 256 blocks (8 units each), block 512 = 8 waves (4 row-quarters x 2 col-halves),
// wave tile 16 rows x 16 packed cols.
template<bool HASK>
__global__ __launch_bounds__(512) void layer_fused(
    const unsigned short* __restrict__ hOld,   // [64][2048] this layer's old h
    const unsigned short* __restrict__ rkP,    // packed recurrent weights [8192][2048]
    const unsigned short* __restrict__ xNew,   // [64][2048] lower layer's NEW h (if HASK)
    const unsigned short* __restrict__ kP,     // packed input weights (if HASK)
    const float* __restrict__ xk0base,         // [64][8192] base (layer 0) or nullptr
    const float* __restrict__ bias,            // [8192] bias (if HASK)
    float* __restrict__ cst,                   // [64][2048] this layer's c (in/out)
    unsigned short* __restrict__ hNew)         // [64][2048] new h (bf16 out)
{
    __shared__ float sg[64][33];
    const int t = threadIdx.x, wv = t >> 6, l = t & 63;
    const int rq = wv & 3, ch = wv >> 2;       // row quarter, col half
    const int lr = l & 15, lk = (l >> 4) * 8;
    const int prow = blockIdx.x * 32 + ch * 16 + lr;   // packed weight row

    f32x4 acc0 = {}, acc1 = {};
    kphase2048(hOld + (size_t)(rq * 16 + lr) * U_ + lk,
               rkP + (size_t)prow * U_ + lk, acc0, acc1);
    if (HASK)
        kphase2048(xNew + (size_t)(rq * 16 + lr) * U_ + lk,
                   kP + (size_t)prow * U_ + lk, acc0, acc1);

    const f32x4 s = acc0 + acc1;
    const int l4 = (l >> 4) * 4;
    #pragma unroll
    for (int r = 0; r < 4; ++r)
        sg[rq * 16 + l4 + r][ch * 16 + lr] = s[r];
    __syncthreads();

    // 512 threads apply the cell for 64 batch x 8 units
    const int b = t >> 3, uu = t & 7;
    const int u = blockIdx.x * 8 + uu;                 // original unit index
    float g[4];
    #pragma unroll
    for (int gi = 0; gi < 4; ++gi) {
        float base = HASK ? bias[gi * 2048 + u]
                          : xk0base[(size_t)b * G4_ + gi * 2048 + u];
        g[gi] = sg[b][gi * 8 + uu] + base;
    }
    float* cp = cst + (size_t)b * U_ + u;
    const float c  = *cp;
    const float cn = sigf(g[1]) * c + sigf(g[0]) * tanhf(g[2]);
    const float hn = sigf(g[3]) * tanhf(cn);
    *cp = cn;
    hNew[(size_t)b * U_ + u] = f2bf(hn);
}

// ---------------- batched output projection: ONE GEMM after the time loop ----------------
__global__ __launch_bounds__(256) void outproj_all(const unsigned short* __restrict__ h2h,
                                                   const unsigned short* __restrict__ w_outT,
                                                   const float* __restrict__ b_out,
                                                   float* __restrict__ out)
{
    const int t = threadIdx.x, wv = t >> 6, l = t & 63;
    const int m0 = blockIdx.x * 64 + wv * 16;
    const int lr = l & 15, lk = (l >> 4) * 8;
    const unsigned short* ap = h2h + (size_t)(m0 + lr) * U_ + lk;
    f32x4 acc[6] = {};
    for (int kt = 0; kt < U_; kt += 32) {
        bf16x8 af = *(const bf16x8*)(ap + kt);
        #pragma unroll
        for (int n = 0; n < 6; ++n) {
            bf16x8 wf = *(const bf16x8*)(w_outT + (size_t)(n * 16 + lr) * U_ + kt + lk);
            acc[n] = MFMA(af, wf, acc[n]);
        }
    }
    const int l4 = (l >> 4) * 4;
    #pragma unroll
    for (int n = 0; n < 6; ++n) {
        const int col = n * 16 + lr;
        if (col < DIN_) {
            #pragma unroll
            for (int r = 0; r < 4; ++r) {
                int row = m0 + l4 + r;                  // = tstep*64 + b
                int tt = row >> 6, b = row & 63;
                out[((size_t)b * T_ + tt) * DIN_ + col] = acc[n][r] + b_out[col];
            }
        }
    }
}

extern "C" void kernel_launch(void* const* d_in, const int* in_sizes, int n_in,
                              void* d_out, int out_size, void* d_ws, size_t ws_size,
                              hipStream_t stream)
{
    const float* z      = (const float*)d_in[0];
    const float* w_init = (const float*)d_in[1];
    const float* b_init = (const float*)d_in[2];
    const float* k0     = (const float*)d_in[3];
    const float* rk0    = (const float*)d_in[4];
    const float* b0     = (const float*)d_in[5];
    const float* k1     = (const float*)d_in[6];
    const float* rk1    = (const float*)d_in[7];
    const float* b1     = (const float*)d_in[8];
    const float* k2     = (const float*)d_in[9];
    const float* rk2    = (const float*)d_in[10];
    const float* b2     = (const float*)d_in[11];
    const float* w_out  = (const float*)d_in[12];
    const float* b_out  = (const float*)d_in[13];
    float* out = (float*)d_out;
    (void)in_sizes; (void)n_in; (void)out_size; (void)ws_size;

    // workspace carve-up (256B aligned), total ~200 MB (+tail pad for prefetch overrun)
    size_t off = 0;
    char* base = (char*)d_ws;
    auto alloc = [&](size_t bytes) { void* p = base + off; off += (bytes + 255) & ~(size_t)255; return p; };
    unsigned short* rk0P = (unsigned short*)alloc((size_t)U_ * G4_ * 2);
    unsigned short* rk1P = (unsigned short*)alloc((size_t)U_ * G4_ * 2);
    unsigned short* rk2P = (unsigned short*)alloc((size_t)U_ * G4_ * 2);
    unsigned short* k1P  = (unsigned short*)alloc((size_t)U_ * G4_ * 2);
    unsigned short* k2P  = (unsigned short*)alloc((size_t)U_ * G4_ * 2);
    unsigned short* wiT  = (unsigned short*)alloc((size_t)STLD * Z_ * 2);
    unsigned short* k0T  = (unsigned short*)alloc((size_t)G4_ * Z_ * 2);
    unsigned short* woT  = (unsigned short*)alloc((size_t)96 * U_ * 2);
    unsigned short* zb   = (unsigned short*)alloc((size_t)B_ * Z_ * 2);
    unsigned short* hb0[2], *hb1[2];
    for (int p = 0; p < 2; ++p) hb0[p] = (unsigned short*)alloc((size_t)B_ * U_ * 2);
    for (int p = 0; p < 2; ++p) hb1[p] = (unsigned short*)alloc((size_t)B_ * U_ * 2);
    unsigned short* h2hist = (unsigned short*)alloc((size_t)(T_ + 1) * B_ * U_ * 2);
    float* st   = (float*)alloc((size_t)B_ * STLD * 4);
    float* xk0  = (float*)alloc((size_t)B_ * G4_ * 4);
    float* cst0 = (float*)alloc((size_t)B_ * U_ * 4);
    float* cst1 = (float*)alloc((size_t)B_ * U_ * 4);
    float* cst2 = (float*)alloc((size_t)B_ * U_ * 4);
    (void)alloc(4096);                                       // tail pad (prefetch overrun)

    // --- one-time conversions ---
    transpose_cvt_packed<<<dim3(G4_ / 32, U_ / 32), 256, 0, stream>>>(rk0, rk0P);
    transpose_cvt_packed<<<dim3(G4_ / 32, U_ / 32), 256, 0, stream>>>(rk1, rk1P);
    transpose_cvt_packed<<<dim3(G4_ / 32, U_ / 32), 256, 0, stream>>>(rk2, rk2P);
    transpose_cvt_packed<<<dim3(G4_ / 32, U_ / 32), 256, 0, stream>>>(k1, k1P);
    transpose_cvt_packed<<<dim3(G4_ / 32, U_ / 32), 256, 0, stream>>>(k2, k2P);
    transpose_cvt<<<dim3(STLD / 32, Z_ / 32), 256, 0, stream>>>(w_init, wiT, Z_, STLD, 0);
    transpose_cvt<<<dim3(G4_ / 32, Z_ / 32), 256, 0, stream>>>(k0, k0T, Z_, G4_, DIN_);
    wout_cvt<<<dim3(96 * U_ / 256), 256, 0, stream>>>(w_out, woT);
    cvt_z<<<dim3(B_ * Z_ / 256), 256, 0, stream>>>(z, zb);

    // --- setup: st = zb @ wiT^T + b_init ; xk0 = zb @ k0T^T + b0 ---
    gemm_plain<<<dim3(STLD / 64), 256, 0, stream>>>(zb, Z_, wiT, b_init, st, STLD);
    gemm_plain<<<dim3(G4_ / 64), 256, 0, stream>>>(zb, Z_, k0T, b0, xk0, G4_);
    hcinit<<<dim3(3 * B_ * U_ / 256), 256, 0, stream>>>(st, hb0[0], hb1[0], h2hist,
                                                        cst0, cst1, cst2);

    // --- time loop: 3 fused launches/step ---
    for (int tstep = 0; tstep < T_; ++tstep) {
        const int p = tstep & 1;
        layer_fused<false><<<dim3(U_ / 8), 512, 0, stream>>>(
            hb0[p], rk0P, nullptr, nullptr, xk0, nullptr, cst0, hb0[p ^ 1]);
        layer_fused<true><<<dim3(U_ / 8), 512, 0, stream>>>(
            hb1[p], rk1P, hb0[p ^ 1], k1P, nullptr, b1, cst1, hb1[p ^ 1]);
        layer_fused<true><<<dim3(U_ / 8), 512, 0, stream>>>(
            h2hist + (size_t)tstep * B_ * U_, rk2P, hb1[p ^ 1], k2P, nullptr, b2,
            cst2, h2hist + (size_t)(tstep + 1) * B_ * U_);
    }
    // --- all 32 output projections in one GEMM ---
    outproj_all<<<dim3(T_ * B_ / 64), 256, 0, stream>>>(h2hist + (size_t)B_ * U_, woT, b_out, out);
}

// Round 9
// 2188.338 us; speedup vs baseline: 2.2706x; 2.2706x over previous
//
#include <hip/hip_runtime.h>
#include <cstdint>

// Problem constants
#define B_   64
#define Z_   512
#define U_   2048
#define T_   32
#define DIN_ 90
#define G4_  8192      // 4*U
#define STLD 12288     // setup GEMM output row stride: h at +l*4096, c at +l*4096+2048

using bf16x8 = __attribute__((ext_vector_type(8))) short;   // 8 bf16 = 4 VGPRs
using f32x4  = __attribute__((ext_vector_type(4))) float;

#define MFMA(a, b, c) __builtin_amdgcn_mfma_f32_16x16x32_bf16((a), (b), (c), 0, 0, 0)

__device__ __forceinline__ unsigned short f2bf(float f) {
    unsigned int u = __float_as_uint(f);
    unsigned int r = (u + 0x7FFFu + ((u >> 16) & 1u)) >> 16;   // RNE
    return (unsigned short)r;
}
__device__ __forceinline__ float sigf(float x) { return 1.f / (1.f + expf(-x)); }

// async global->LDS, 16 B per lane; LDS dest is wave-uniform base + lane*16
__device__ __forceinline__ void gld16(const void* g, void* l) {
    __builtin_amdgcn_global_load_lds(
        (const __attribute__((address_space(1))) unsigned int*)g,
        (__attribute__((address_space(3))) unsigned int*)l, 16, 0, 0);
}

// ---------------- one-time weight prep ----------------

// Plain transpose: Wt[n*K + k] = bf16(W[(row_off+k)*N + n])
__global__ __launch_bounds__(256) void transpose_cvt(const float* __restrict__ W,
                                                     unsigned short* __restrict__ Wt,
                                                     int K, int N, int row_off)
{
    __shared__ float tile[32][33];
    const int nb = blockIdx.x * 32, kb = blockIdx.y * 32;
    const int tx = threadIdx.x & 31, ty = threadIdx.x >> 5;   // 32 x 8
    #pragma unroll
    for (int i = 0; i < 4; ++i)
        tile[ty + i * 8][tx] = W[(size_t)(row_off + kb + ty + i * 8) * N + nb + tx];
    __syncthreads();
    #pragma unroll
    for (int i = 0; i < 4; ++i)
        Wt[(size_t)(nb + ty + i * 8) * K + kb + tx] = f2bf(tile[tx][ty + i * 8]);
}

// Packed transpose: original col n = g*2048+u -> packed row (u>>3)*32 + g*8 + (u&7).
// Unit-tile block bx then owns packed rows [bx*32, bx*32+32).
__global__ __launch_bounds__(256) void transpose_cvt_packed(const float* __restrict__ W,
                                                            unsigned short* __restrict__ Wt)
{
    __shared__ float tile[32][33];
    const int nb = blockIdx.x * 32, kb = blockIdx.y * 32;   // N=8192, K=2048
    const int tx = threadIdx.x & 31, ty = threadIdx.x >> 5;
    #pragma unroll
    for (int i = 0; i < 4; ++i)
        tile[ty + i * 8][tx] = W[(size_t)(kb + ty + i * 8) * G4_ + nb + tx];
    __syncthreads();
    #pragma unroll
    for (int i = 0; i < 4; ++i) {
        int n = nb + ty + i * 8;
        int g = n >> 11, u = n & 2047;
        int prow = ((u >> 3) << 5) + (g << 3) + (u & 7);
        Wt[(size_t)prow * U_ + kb + tx] = f2bf(tile[tx][ty + i * 8]);
    }
}

// w_outT[d][k] = bf16(w_out[k*90+d]) for d<90, else 0   (96 x 2048)
__global__ __launch_bounds__(256) void wout_cvt(const float* __restrict__ w_out,
                                                unsigned short* __restrict__ w_outT)
{
    int i = blockIdx.x * 256 + threadIdx.x;        // 96*2048
    int d = i >> 11, k = i & 2047;
    w_outT[i] = (d < DIN_) ? f2bf(w_out[(size_t)k * DIN_ + d]) : (unsigned short)0;
}

__global__ __launch_bounds__(256) void cvt_z(const float* __restrict__ z,
                                             unsigned short* __restrict__ zb)
{
    int i = blockIdx.x * 256 + threadIdx.x;        // 64*512
    zb[i] = f2bf(z[i]);
}

// initial h (bf16) and c (fp32) from the setup GEMM output st
__global__ __launch_bounds__(256) void hcinit(const float* __restrict__ st,
                                              unsigned short* __restrict__ h0,
                                              unsigned short* __restrict__ h1,
                                              unsigned short* __restrict__ h2s0,
                                              float* __restrict__ c0,
                                              float* __restrict__ c1,
                                              float* __restrict__ c2)
{
    int idx = blockIdx.x * 256 + threadIdx.x;      // 3*64*2048
    int u = idx & 2047, b = (idx >> 11) & 63, ly = idx >> 17;
    float hv = st[(size_t)b * STLD + ly * 4096 + u];
    float cv = st[(size_t)b * STLD + ly * 4096 + 2048 + u];
    unsigned short* h = (ly == 0) ? h0 : (ly == 1) ? h1 : h2s0;
    float* c = (ly == 0) ? c0 : (ly == 1) ? c1 : c2;
    h[(size_t)b * 2048 + u] = f2bf(hv);
    c[(size_t)b * 2048 + u] = cv;
}

// ---------------- setup GEMMs (K=512): out[64 x N] = A @ Wt^T + bias ----------------
__global__ __launch_bounds__(256) void gemm_plain(const unsigned short* __restrict__ A, int K,
                                                  const unsigned short* __restrict__ Wt,
                                                  const float* __restrict__ bias,
                                                  float* __restrict__ out, int ldo)
{
    const int t = threadIdx.x, wv = t >> 6, l = t & 63;
    const int wm = (wv >> 1) * 32, n0 = blockIdx.x * 64 + (wv & 1) * 32;
    const int lr = l & 15, lk = (l >> 4) * 8;
    f32x4 acc[2][2] = {};
    for (int kt = 0; kt < K; kt += 32) {
        bf16x8 a0 = *(const bf16x8*)(A + (size_t)(wm + lr) * K + kt + lk);
        bf16x8 a1 = *(const bf16x8*)(A + (size_t)(wm + 16 + lr) * K + kt + lk);
        bf16x8 w0 = *(const bf16x8*)(Wt + (size_t)(n0 + lr) * K + kt + lk);
        bf16x8 w1 = *(const bf16x8*)(Wt + (size_t)(n0 + 16 + lr) * K + kt + lk);
        acc[0][0] = MFMA(a0, w0, acc[0][0]);
        acc[0][1] = MFMA(a0, w1, acc[0][1]);
        acc[1][0] = MFMA(a1, w0, acc[1][0]);
        acc[1][1] = MFMA(a1, w1, acc[1][1]);
    }
    #pragma unroll
    for (int mi = 0; mi < 2; ++mi)
        #pragma unroll
        for (int ni = 0; ni < 2; ++ni)
            #pragma unroll
            for (int r = 0; r < 4; ++r) {
                int row = wm + mi * 16 + (l >> 4) * 4 + r;
                int col = n0 + ni * 16 + lr;
                out[(size_t)row * ldo + col] = acc[mi][ni][r] + bias[col];
            }
}

// ---------------- fused per-layer step kernel (global_load_lds staged) ----------------
// grid (256 unit-tiles, 2 row-halves), block 256 = 4 waves (rq = wv&1 row-half-of-32,
// ch = wv>>1 col-half-of-32), wave tile 16x16. KT=128; stage = A 32x128 + W 32x128
// (8+8 KB); 3 stages; counted vmcnt(4). XOR swizzle (T2): LDS byte-in-row ^= (row&7)<<4,
// applied to the GLOBAL source (inverse) and to the ds_read address (same involution).
template<bool HASK>
__global__ __launch_bounds__(256) void layer_fused(
    const unsigned short* __restrict__ hOld,   // [64][2048] this layer's old h
    const unsigned short* __restrict__ rkP,    // packed recurrent weights [8192][2048]
    const unsigned short* __restrict__ xNew,   // [64][2048] lower layer's NEW h (if HASK)
    const unsigned short* __restrict__ kP,     // packed input weights (if HASK)
    const float* __restrict__ xk0base,         // [64][8192] base (layer 0) or nullptr
    const float* __restrict__ bias,            // [8192] bias (if HASK)
    float* __restrict__ cst,                   // [64][2048] this layer's c (in/out)
    unsigned short* __restrict__ hNew)         // [64][2048] new h (bf16 out)
{
    __shared__ char  stg[3 * 16384];           // 3 stages x (A 8KB | W 8KB)
    __shared__ float sg[32][33];
    const int t = threadIdx.x, wv = t >> 6, l = t & 63;
    const int rbase = blockIdx.y * 32;         // batch rows this block owns
    const int prow0 = blockIdx.x * 32;         // packed weight rows this block owns
    const int NT = HASK ? 32 : 16;             // k-tiles total (2 phases if HASK)

    // ---- per-lane staging geometry (tile-invariant) ----
    size_t ag[2], wg[2];
    unsigned al[2], wl[2];
    #pragma unroll
    for (int c = 0; c < 2; ++c) {
        int idx = (c * 4 + wv) * 64 + l;               // 0..511
        int row = idx >> 4, kb = (idx & 15) << 4;      // row 0..31, 16B chunk
        int sw = kb ^ ((row & 7) << 4);                // inverse swizzle on source
        ag[c] = (size_t)(rbase + row) * U_ + (sw >> 1);
        al[c] = (c * 4 + wv) * 1024;
        wg[c] = (size_t)(prow0 + row) * U_ + (sw >> 1);
        wl[c] = 8192 + (c * 4 + wv) * 1024;
    }
    // ---- per-lane compute geometry ----
    const int rq = wv & 1, ch = wv >> 1;
    const int lr = l & 15, lkb = (l >> 4) << 4;
    int aoff[4], woff[4];
    #pragma unroll
    for (int ks = 0; ks < 4; ++ks) {
        int kb = ks * 64 + lkb;
        int ar = rq * 16 + lr, wr = ch * 16 + lr;
        aoff[ks] = ar * 256 + (kb ^ ((ar & 7) << 4));
        woff[ks] = 8192 + wr * 256 + (kb ^ ((wr & 7) << 4));
    }

    auto issue = [&](int tt) {
        const unsigned short* As = (HASK && tt >= 16) ? xNew : hOld;
        const unsigned short* Ws = (HASK && tt >= 16) ? kP : rkP;
        const int k0 = (tt & 15) * 128;
        char* sb = stg + (tt % 3) * 16384;
        gld16(As + ag[0] + k0, sb + al[0]);
        gld16(As + ag[1] + k0, sb + al[1]);
        gld16(Ws + wg[0] + k0, sb + wl[0]);
        gld16(Ws + wg[1] + k0, sb + wl[1]);
    };

    f32x4 acc = {};
    issue(0);
    issue(1);
    for (int tt = 0; tt < NT; ++tt) {
        if (tt < NT - 1) asm volatile("s_waitcnt vmcnt(4)" ::: "memory");
        else             asm volatile("s_waitcnt vmcnt(0)" ::: "memory");
        __builtin_amdgcn_s_barrier();
        if (tt + 2 < NT) issue(tt + 2);
        const char* sb = stg + (tt % 3) * 16384;
        #pragma unroll
        for (int ks = 0; ks < 4; ++ks) {
            bf16x8 av = *(const bf16x8*)(sb + aoff[ks]);
            bf16x8 wf = *(const bf16x8*)(sb + woff[ks]);
            acc = MFMA(av, wf, acc);
        }
    }

    // ---- gate epilogue: 32 rows x 8 units, exactly 256 threads ----
    const int l4 = (l >> 4) << 2;
    #pragma unroll
    for (int r = 0; r < 4; ++r)
        sg[rq * 16 + l4 + r][ch * 16 + lr] = acc[r];
    __syncthreads();

    const int bl = t >> 3, uu = t & 7;
    const int b = rbase + bl, u = blockIdx.x * 8 + uu;
    float g[4];
    #pragma unroll
    for (int gi = 0; gi < 4; ++gi) {
        float base = HASK ? bias[gi * 2048 + u]
                          : xk0base[(size_t)b * G4_ + gi * 2048 + u];
        g[gi] = sg[bl][gi * 8 + uu] + base;
    }
    float* cp = cst + (size_t)b * U_ + u;
    const float c  = *cp;
    const float cn = sigf(g[1]) * c + sigf(g[0]) * tanhf(g[2]);
    const float hn = sigf(g[3]) * tanhf(cn);
    *cp = cn;
    hNew[(size_t)b * U_ + u] = f2bf(hn);
}

// ---------------- batched output projection: ONE GEMM after the time loop ----------------
__global__ __launch_bounds__(256) void outproj_all(const unsigned short* __restrict__ h2h,
                                                   const unsigned short* __restrict__ w_outT,
                                                   const float* __restrict__ b_out,
                                                   float* __restrict__ out)
{
    const int t = threadIdx.x, wv = t >> 6, l = t & 63;
    const int m0 = blockIdx.x * 64 + wv * 16;
    const int lr = l & 15, lk = (l >> 4) * 8;
    const unsigned short* ap = h2h + (size_t)(m0 + lr) * U_ + lk;
    f32x4 acc[6] = {};
    for (int kt = 0; kt < U_; kt += 32) {
        bf16x8 af = *(const bf16x8*)(ap + kt);
        #pragma unroll
        for (int n = 0; n < 6; ++n) {
            bf16x8 wf = *(const bf16x8*)(w_outT + (size_t)(n * 16 + lr) * U_ + kt + lk);
            acc[n] = MFMA(af, wf, acc[n]);
        }
    }
    const int l4 = (l >> 4) * 4;
    #pragma unroll
    for (int n = 0; n < 6; ++n) {
        const int col = n * 16 + lr;
        if (col < DIN_) {
            #pragma unroll
            for (int r = 0; r < 4; ++r) {
                int row = m0 + l4 + r;                  // = tstep*64 + b
                int tt = row >> 6, b = row & 63;
                out[((size_t)b * T_ + tt) * DIN_ + col] = acc[n][r] + b_out[col];
            }
        }
    }
}

extern "C" void kernel_launch(void* const* d_in, const int* in_sizes, int n_in,
                              void* d_out, int out_size, void* d_ws, size_t ws_size,
                              hipStream_t stream)
{
    const float* z      = (const float*)d_in[0];
    const float* w_init = (const float*)d_in[1];
    const float* b_init = (const float*)d_in[2];
    const float* k0     = (const float*)d_in[3];
    const float* rk0    = (const float*)d_in[4];
    const float* b0     = (const float*)d_in[5];
    const float* k1     = (const float*)d_in[6];
    const float* rk1    = (const float*)d_in[7];
    const float* b1     = (const float*)d_in[8];
    const float* k2     = (const float*)d_in[9];
    const float* rk2    = (const float*)d_in[10];
    const float* b2     = (const float*)d_in[11];
    const float* w_out  = (const float*)d_in[12];
    const float* b_out  = (const float*)d_in[13];
    float* out = (float*)d_out;
    (void)in_sizes; (void)n_in; (void)out_size; (void)ws_size;

    // workspace carve-up (256B aligned), total ~200 MB
    size_t off = 0;
    char* base = (char*)d_ws;
    auto alloc = [&](size_t bytes) { void* p = base + off; off += (bytes + 255) & ~(size_t)255; return p; };
    unsigned short* rk0P = (unsigned short*)alloc((size_t)U_ * G4_ * 2);
    unsigned short* rk1P = (unsigned short*)alloc((size_t)U_ * G4_ * 2);
    unsigned short* rk2P = (unsigned short*)alloc((size_t)U_ * G4_ * 2);
    unsigned short* k1P  = (unsigned short*)alloc((size_t)U_ * G4_ * 2);
    unsigned short* k2P  = (unsigned short*)alloc((size_t)U_ * G4_ * 2);
    unsigned short* wiT  = (unsigned short*)alloc((size_t)STLD * Z_ * 2);
    unsigned short* k0T  = (unsigned short*)alloc((size_t)G4_ * Z_ * 2);
    unsigned short* woT  = (unsigned short*)alloc((size_t)96 * U_ * 2);
    unsigned short* zb   = (unsigned short*)alloc((size_t)B_ * Z_ * 2);
    unsigned short* hb0[2], *hb1[2];
    for (int p = 0; p < 2; ++p) hb0[p] = (unsigned short*)alloc((size_t)B_ * U_ * 2);
    for (int p = 0; p < 2; ++p) hb1[p] = (unsigned short*)alloc((size_t)B_ * U_ * 2);
    unsigned short* h2hist = (unsigned short*)alloc((size_t)(T_ + 1) * B_ * U_ * 2);
    float* st   = (float*)alloc((size_t)B_ * STLD * 4);
    float* xk0  = (float*)alloc((size_t)B_ * G4_ * 4);
    float* cst0 = (float*)alloc((size_t)B_ * U_ * 4);
    float* cst1 = (float*)alloc((size_t)B_ * U_ * 4);
    float* cst2 = (float*)alloc((size_t)B_ * U_ * 4);

    // --- one-time conversions ---
    transpose_cvt_packed<<<dim3(G4_ / 32, U_ / 32), 256, 0, stream>>>(rk0, rk0P);
    transpose_cvt_packed<<<dim3(G4_ / 32, U_ / 32), 256, 0, stream>>>(rk1, rk1P);
    transpose_cvt_packed<<<dim3(G4_ / 32, U_ / 32), 256, 0, stream>>>(rk2, rk2P);
    transpose_cvt_packed<<<dim3(G4_ / 32, U_ / 32), 256, 0, stream>>>(k1, k1P);
    transpose_cvt_packed<<<dim3(G4_ / 32, U_ / 32), 256, 0, stream>>>(k2, k2P);
    transpose_cvt<<<dim3(STLD / 32, Z_ / 32), 256, 0, stream>>>(w_init, wiT, Z_, STLD, 0);
    transpose_cvt<<<dim3(G4_ / 32, Z_ / 32), 256, 0, stream>>>(k0, k0T, Z_, G4_, DIN_);
    wout_cvt<<<dim3(96 * U_ / 256), 256, 0, stream>>>(w_out, woT);
    cvt_z<<<dim3(B_ * Z_ / 256), 256, 0, stream>>>(z, zb);

    // --- setup: st = zb @ wiT^T + b_init ; xk0 = zb @ k0T^T + b0 ---
    gemm_plain<<<dim3(STLD / 64), 256, 0, stream>>>(zb, Z_, wiT, b_init, st, STLD);
    gemm_plain<<<dim3(G4_ / 64), 256, 0, stream>>>(zb, Z_, k0T, b0, xk0, G4_);
    hcinit<<<dim3(3 * B_ * U_ / 256), 256, 0, stream>>>(st, hb0[0], hb1[0], h2hist,
                                                        cst0, cst1, cst2);

    // --- time loop: 3 fused launches/step ---
    for (int tstep = 0; tstep < T_; ++tstep) {
        const int p = tstep & 1;
        layer_fused<false><<<dim3(U_ / 8, 2), 256, 0, stream>>>(
            hb0[p], rk0P, nullptr, nullptr, xk0, nullptr, cst0, hb0[p ^ 1]);
        layer_fused<true><<<dim3(U_ / 8, 2), 256, 0, stream>>>(
            hb1[p], rk1P, hb0[p ^ 1], k1P, nullptr, b1, cst1, hb1[p ^ 1]);
        layer_fused<true><<<dim3(U_ / 8, 2), 256, 0, stream>>>(
            h2hist + (size_t)tstep * B_ * U_, rk2P, hb1[p ^ 1], k2P, nullptr, b2,
            cst2, h2hist + (size_t)(tstep + 1) * B_ * U_);
    }
    // --- all 32 output projections in one GEMM ---
    outproj_all<<<dim3(T_ * B_ / 64), 256, 0, stream>>>(h2hist + (size_t)B_ * U_, woT, b_out, out);
}